// Round 21
// baseline (103.639 us; speedup 1.0000x reference)
//
#include <hip/hip_runtime.h>
#include <hip/hip_bf16.h>
#include <stdint.h>

#define B_    4
#define N_    2048
#define M_    2048
#define DIMX  512
#define INNER 512
#define H_    8
#define DH    64
#define MK    2049   // M+1 keys; null token lives at key index 2048
#define MKP   2112   // padded to 33 tiles of 64 (tail masked in-kernel)

#define QSCALE  0.18033688011f   // 0.125 * log2(e): softmax in exp2 domain
#define SM_BIAS -11.5415605f     // static softmax max: |S_log2| <= 64*QSCALE

using u16 = unsigned short;
using u32 = unsigned int;

typedef __attribute__((ext_vector_type(8))) short short8;
typedef __attribute__((ext_vector_type(4))) float f32x4;

#if defined(__has_builtin)
# if __has_builtin(__builtin_amdgcn_exp2f)
#  define EXP2(x) __builtin_amdgcn_exp2f(x)
# endif
#endif
#ifndef EXP2
# define EXP2(x) exp2f(x)
#endif

__device__ __forceinline__ u16 bfc(float f){
  __hip_bfloat16 h = __float2bfloat16(f);
  return *reinterpret_cast<u16*>(&h);
}
__device__ __forceinline__ u32 bfpk(float lo, float hi){
  return (u32)bfc(lo) | ((u32)bfc(hi) << 16);
}
// Truncation pack for P only: downward bias cancels to first order in
// O = (P@V)/(P@ones) since numerator and denominator use the SAME bits.
__device__ __forceinline__ u32 bfpk_tr(float lo, float hi){
  union { float f; u32 u; } a, b; a.f = lo; b.f = hi;
  return (a.u >> 16) | (b.u & 0xffff0000u);
}

// direct global->LDS 16B copy: LDS dest = wave-uniform base + lane*16;
// per-lane global source carries the swizzle (m173 pattern). Completion is
// guaranteed by __syncthreads (drains vmcnt(0) before s_barrier).
__device__ __forceinline__ void gload16(const void* g, void* l){
  __builtin_amdgcn_global_load_lds(
      (const __attribute__((address_space(1))) unsigned int*)g,
      (__attribute__((address_space(3))) unsigned int*)l, 16, 0, 0);
}

// ---------------------------------------------------------------------------
// Merged prep: one dispatch.
//  blocks [0, 2048)     : x  fp32 -> bf16 (8 elems/thread)
//  blocks [2048, 4096)  : ctx fp32 -> bf16
//  blocks [4096, 4480)  : weight transposes fp32 [R][C] -> bf16 [C][R]
//  blocks [4480, 4488)  : null token fill at key index 2048 (k & v^T),
//                         at PRE-SWIZZLED chunk slots (r14's missed bug).
// ---------------------------------------------------------------------------
__global__ __launch_bounds__(256) void prep(
    const float* __restrict__ x, const float* __restrict__ ctx,
    const float* __restrict__ Wq, const float* __restrict__ Wkv,
    const float* __restrict__ Wout,
    const float* __restrict__ nk, const float* __restrict__ nv,
    u16* __restrict__ xb, u16* __restrict__ cb,
    u16* __restrict__ Wqt, u16* __restrict__ Wkvt, u16* __restrict__ Woutt,
    u16* __restrict__ kb, u16* __restrict__ vt)
{
  const int bid = blockIdx.x;
  if (bid < 4096){                       // streaming converts
    const float* in = (bid < 2048) ? x : ctx;
    u16* out        = (bid < 2048) ? xb : cb;
    const int i = (bid & 2047) * 256 + threadIdx.x;
    float4 a = ((const float4*)in)[i*2];
    float4 b = ((const float4*)in)[i*2+1];
    uint4 t;
    t.x = bfpk(a.x, a.y); t.y = bfpk(a.z, a.w);
    t.z = bfpk(b.x, b.y); t.w = bfpk(b.z, b.w);
    ((uint4*)out)[i] = t;
    return;
  }
  if (bid >= 4480){                      // null token at key index 2048
    const int i = (bid - 4480) * 256 + threadIdx.x;  // 0..2047 = bh*64 + d
    const int d = i & 63, bh = i >> 6;
    // k: key&7 == 0 -> chunk slot for dim d is (d>>3)^0 = d>>3 -> linear
    kb[((size_t)bh * MKP + 2048) * DH + d] = bfc(tanhf(nk[d]));
    // v^T: key 2048 = chunk 0 of its tile -> slot 0^(d&7), offset 0
    vt[((size_t)bh * DH + d) * MKP + 2048 + ((d & 7) << 3)] = bfc(nv[d]);
    return;
  }
  // weight transposes: 384 blocks = 3 x (16 x 8)
  const int tt = bid - 4096;
  const int z  = tt >> 7;                // 0..2
  const int rem = tt & 127;
  const int cx = rem & 15, ry = rem >> 4;
  const float* in = (z == 0) ? Wq : (z == 1) ? Wkv : Wout;
  u16* out        = (z == 0) ? Wqt : (z == 1) ? Wkvt : Woutt;
  const int C     = (z == 1) ? 1024 : 512;
  const int R     = 512;
  if (cx * 64 >= C) return;

  __shared__ float tl[64][65];
  const int t = threadIdx.x;
  const int c0 = cx * 64, r0 = ry * 64;
  const int col = t & 63, rb = t >> 6;
  #pragma unroll
  for (int j = 0; j < 16; ++j){
    const int row = rb + j*4;
    tl[row][col] = in[(size_t)(r0 + row) * C + c0 + col];
  }
  __syncthreads();
  #pragma unroll
  for (int j = 0; j < 16; ++j){
    const int orow = rb + j*4;
    out[(size_t)(c0 + orow) * R + r0 + col] = bfc(tl[col][orow]);
  }
}

// frag-read + 16 MFMA from LDS buffer `bi` (compile-time)
#define PROJ_COMPUTE(bi)                                                      \
  {                                                                           \
    short8 af[4], bf[4];                                                      \
    _Pragma("unroll")                                                         \
    for (int m = 0; m < 4; ++m){                                              \
      const int row = wr + m*16 + c;                                          \
      af[m] = *(const short8*)((char*)At[bi] + row*64 + ((g ^ ((row>>1)&3)) << 4)); \
    }                                                                         \
    _Pragma("unroll")                                                         \
    for (int n = 0; n < 4; ++n){                                              \
      const int row = wc + n*16 + c;                                          \
      bf[n] = *(const short8*)((char*)Bl[bi] + row*64 + ((g ^ ((row>>1)&3)) << 4)); \
    }                                                                         \
    __builtin_amdgcn_s_setprio(1);                                            \
    _Pragma("unroll")                                                         \
    for (int m = 0; m < 4; ++m)                                               \
      _Pragma("unroll")                                                       \
      for (int n = 0; n < 4; ++n)                                             \
        acc[m][n] = __builtin_amdgcn_mfma_f32_16x16x32_bf16(af[m], bf[n], acc[m][n], 0, 0, 0); \
    __builtin_amdgcn_s_setprio(0);                                            \
  }

// ---------------------------------------------------------------------------
// Fused q + kv projection GEMM, all-bf16 inputs. 768 blocks (XCD-chunked).
// 128x128 tile, BK=32, depth-2 register prefetch + double-buffered LDS.
// k and v^T are written with PRE-SWIZZLED 16B chunks (chunk slot ^= key&7 for
// k rows; ^= dim&7 for v^T rows) so attention stages them with linear
// global_load_lds while keeping conflict-free swizzled reads.
// ---------------------------------------------------------------------------
__global__ __launch_bounds__(256, 3) void fused_proj(
    const u16* __restrict__ xb, const u16* __restrict__ cb,
    const u16* __restrict__ Wqt, const u16* __restrict__ Wkvt,
    u16* __restrict__ qb, u16* __restrict__ kb, u16* __restrict__ vt)
{
  __shared__ __align__(16) short At[2][128*32];
  __shared__ __align__(16) short Bl[2][128*32];

  const int flat = blockIdx.x;
  const int tile = (flat & 7) * 96 + (flat >> 3);    // XCD-chunked, bijective
  const bool isq = tile < 256;
  const int lt   = isq ? tile : tile - 256;
  const int gx   = isq ? 4 : 8;
  const int row0 = (lt / gx) * 128, col0 = (lt % gx) * 128;
  const u16* A  = isq ? xb : cb;
  const u16* Bt = isq ? Wqt : Wkvt;

  const int tid = threadIdx.x;
  const int w = tid >> 6, lane = tid & 63;
  const int c = lane & 15, g = lane >> 4;
  const int wr = (w >> 1) * 64, wc = (w & 1) * 64;

  f32x4 acc[4][4] = {};

  const int srow = tid >> 1, sj = (tid & 1) * 2;
  const int swz0 = ((sj  ) ^ ((srow >> 1) & 3)) << 4;
  const int swz1 = ((sj+1) ^ ((srow >> 1) & 3)) << 4;

  const u16* asrc = A  + (size_t)(row0 + srow) * DIMX + sj*8;
  const u16* bsrc = Bt + (size_t)(col0 + srow) * DIMX + sj*8;

  uint4 aA0, aA1, bA0, bA1;      // slot A
  uint4 aB0, aB1, bB0, bB1;      // slot B

  aA0 = ((const uint4*)asrc)[0];        aA1 = ((const uint4*)asrc)[1];
  bA0 = ((const uint4*)bsrc)[0];        bA1 = ((const uint4*)bsrc)[1];
  aB0 = ((const uint4*)(asrc + 32))[0]; aB1 = ((const uint4*)(asrc + 32))[1];
  bB0 = ((const uint4*)(bsrc + 32))[0]; bB1 = ((const uint4*)(bsrc + 32))[1];
  *(uint4*)((char*)At[0] + srow*64 + swz0) = aA0;
  *(uint4*)((char*)At[0] + srow*64 + swz1) = aA1;
  *(uint4*)((char*)Bl[0] + srow*64 + swz0) = bA0;
  *(uint4*)((char*)Bl[0] + srow*64 + swz1) = bA1;

  for (int kk = 0; kk < 16; kk += 2){
    __syncthreads();
    if (kk + 2 < 16){
      const u16* an = asrc + (kk+2)*32;
      const u16* bn = bsrc + (kk+2)*32;
      aA0 = ((const uint4*)an)[0]; aA1 = ((const uint4*)an)[1];
      bA0 = ((const uint4*)bn)[0]; bA1 = ((const uint4*)bn)[1];
    }
    PROJ_COMPUTE(0);
    *(uint4*)((char*)At[1] + srow*64 + swz0) = aB0;   // tile kk+1 (always valid)
    *(uint4*)((char*)At[1] + srow*64 + swz1) = aB1;
    *(uint4*)((char*)Bl[1] + srow*64 + swz0) = bB0;
    *(uint4*)((char*)Bl[1] + srow*64 + swz1) = bB1;

    __syncthreads();
    if (kk + 3 < 16){
      const u16* an = asrc + (kk+3)*32;
      const u16* bn = bsrc + (kk+3)*32;
      aB0 = ((const uint4*)an)[0]; aB1 = ((const uint4*)an)[1];
      bB0 = ((const uint4*)bn)[0]; bB1 = ((const uint4*)bn)[1];
    }
    PROJ_COMPUTE(1);
    if (kk + 2 < 16){
      *(uint4*)((char*)At[0] + srow*64 + swz0) = aA0; // tile kk+2
      *(uint4*)((char*)At[0] + srow*64 + swz1) = aA1;
      *(uint4*)((char*)Bl[0] + srow*64 + swz0) = bA0;
      *(uint4*)((char*)Bl[0] + srow*64 + swz1) = bA1;
    }
  }

  #pragma unroll
  for (int m = 0; m < 4; ++m){
    #pragma unroll
    for (int n = 0; n < 4; ++n){
      const int R0  = row0 + wr + m*16 + g*4;
      const int col = col0 + wc + n*16 + c;
      if (isq){
        #pragma unroll
        for (int rr = 0; rr < 4; ++rr)
          qb[(size_t)(R0 + rr) * INNER + col] = bfc(tanhf(acc[m][n][rr]) * QSCALE);
      } else {
        const int bidx = R0 >> 11, mm = R0 & 2047;    // 4 rows share bidx
        if (col < INNER){
          const int h = col >> 6, d = col & 63;
          #pragma unroll
          for (int rr = 0; rr < 4; ++rr){
            const int key = mm + rr;
            const int dsw = (((d >> 3) ^ (key & 7)) << 3) | (d & 7); // pre-swizzle
            kb[((size_t)(bidx*H_ + h) * MKP + key) * DH + dsw] =
                bfc(tanhf(acc[m][n][rr]));
          }
        } else {
          const int cc = col - INNER;
          const int h = cc >> 6, d = cc & 63;
          const int tb = mm & ~63;                     // 64-key tile base
          const int sl = ((mm & 63) >> 3) ^ (d & 7);   // pre-swizzled chunk slot
          uint2 o;                                     // 4 consecutive m -> 8B
          o.x = bfpk(acc[m][n][0], acc[m][n][1]);
          o.y = bfpk(acc[m][n][2], acc[m][n][3]);
          *(uint2*)(vt + ((size_t)(bidx*H_ + h) * DH + d) * MKP
                    + tb + (sl << 3) + (mm & 7)) = o;
        }
      }
    }
  }
}

// ---------------------------------------------------------------------------
// Out-projection GEMM: out = ao @ Wout^T + bias. 128x64 tiles, 512 blocks.
// ---------------------------------------------------------------------------
__global__ __launch_bounds__(256, 3) void mgemm_out(
    const u16* __restrict__ A, const u16* __restrict__ Bt,
    float* __restrict__ Cf, const float* __restrict__ bias)
{
  __shared__ __align__(16) short At[2][128*32];   // 8KB each
  __shared__ __align__(16) short Bl[2][64*32];    // 4KB each

  const int flat = blockIdx.x;                       // 512 blocks
  const int tile = (flat & 7) * 64 + (flat >> 3);    // XCD-chunked, bijective
  const int row0 = (tile >> 3) * 128, col0 = (tile & 7) * 64;

  const int tid = threadIdx.x;
  const int w = tid >> 6, lane = tid & 63;
  const int c = lane & 15, g = lane >> 4;
  const int wr = (w >> 1) * 64, wc = (w & 1) * 32;

  f32x4 acc[4][2] = {};

  const int srow = tid >> 1, sj = (tid & 1) * 2;
  const int swz0 = ((sj  ) ^ ((srow >> 1) & 3)) << 4;
  const int swz1 = ((sj+1) ^ ((srow >> 1) & 3)) << 4;
  const int brow = tid >> 2, bch = tid & 3;
  const int bswz = (bch ^ ((brow >> 1) & 3)) << 4;

  const u16* asrc = A  + (size_t)(row0 + srow) * INNER + sj*8;
  const u16* bsrc = Bt + (size_t)(col0 + brow) * INNER + bch*8;

  uint4 aA0, aA1, bA0;
  uint4 aB0, aB1, bB0;

  aA0 = ((const uint4*)asrc)[0];        aA1 = ((const uint4*)asrc)[1];
  bA0 = *(const uint4*)bsrc;
  aB0 = ((const uint4*)(asrc + 32))[0]; aB1 = ((const uint4*)(asrc + 32))[1];
  bB0 = *(const uint4*)(bsrc + 32);
  *(uint4*)((char*)At[0] + srow*64 + swz0) = aA0;
  *(uint4*)((char*)At[0] + srow*64 + swz1) = aA1;
  *(uint4*)((char*)Bl[0] + brow*64 + bswz) = bA0;

  for (int kk = 0; kk < 16; kk += 2){
    __syncthreads();
    if (kk + 2 < 16){
      const u16* an = asrc + (kk+2)*32;
      aA0 = ((const uint4*)an)[0]; aA1 = ((const uint4*)an)[1];
      bA0 = *(const uint4*)(bsrc + (kk+2)*32);
    }
    {
      short8 af[4], bf[2];
      #pragma unroll
      for (int m = 0; m < 4; ++m){
        const int row = wr + m*16 + c;
        af[m] = *(const short8*)((char*)At[0] + row*64 + ((g ^ ((row>>1)&3)) << 4));
      }
      #pragma unroll
      for (int n = 0; n < 2; ++n){
        const int row = wc + n*16 + c;
        bf[n] = *(const short8*)((char*)Bl[0] + row*64 + ((g ^ ((row>>1)&3)) << 4));
      }
      __builtin_amdgcn_s_setprio(1);
      #pragma unroll
      for (int m = 0; m < 4; ++m)
        #pragma unroll
        for (int n = 0; n < 2; ++n)
          acc[m][n] = __builtin_amdgcn_mfma_f32_16x16x32_bf16(af[m], bf[n], acc[m][n], 0, 0, 0);
      __builtin_amdgcn_s_setprio(0);
    }
    *(uint4*)((char*)At[1] + srow*64 + swz0) = aB0;   // tile kk+1
    *(uint4*)((char*)At[1] + srow*64 + swz1) = aB1;
    *(uint4*)((char*)Bl[1] + brow*64 + bswz) = bB0;

    __syncthreads();
    if (kk + 3 < 16){
      const u16* an = asrc + (kk+3)*32;
      aB0 = ((const uint4*)an)[0]; aB1 = ((const uint4*)an)[1];
      bB0 = *(const uint4*)(bsrc + (kk+3)*32);
    }
    {
      short8 af[4], bf[2];
      #pragma unroll
      for (int m = 0; m < 4; ++m){
        const int row = wr + m*16 + c;
        af[m] = *(const short8*)((char*)At[1] + row*64 + ((g ^ ((row>>1)&3)) << 4));
      }
      #pragma unroll
      for (int n = 0; n < 2; ++n){
        const int row = wc + n*16 + c;
        bf[n] = *(const short8*)((char*)Bl[1] + row*64 + ((g ^ ((row>>1)&3)) << 4));
      }
      __builtin_amdgcn_s_setprio(1);
      #pragma unroll
      for (int m = 0; m < 4; ++m)
        #pragma unroll
        for (int n = 0; n < 2; ++n)
          acc[m][n] = __builtin_amdgcn_mfma_f32_16x16x32_bf16(af[m], bf[n], acc[m][n], 0, 0, 0);
      __builtin_amdgcn_s_setprio(0);
    }
    if (kk + 2 < 16){
      *(uint4*)((char*)At[0] + srow*64 + swz0) = aA0; // tile kk+2
      *(uint4*)((char*)At[0] + srow*64 + swz1) = aA1;
      *(uint4*)((char*)Bl[0] + brow*64 + bswz) = bA0;
    }
  }

  #pragma unroll
  for (int m = 0; m < 4; ++m){
    #pragma unroll
    for (int n = 0; n < 2; ++n){
      #pragma unroll
      for (int rr = 0; rr < 4; ++rr){
        const int R = row0 + wr + m*16 + g*4 + rr;
        const int col = col0 + wc + n*16 + c;
        Cf[(size_t)R * 512 + col] = acc[m][n][rr] + bias[col];
      }
    }
  }
}

// ---------------------------------------------------------------------------
// MFMA flash attention — r17/r20 structure, staging switched to
// global_load_lds from pre-swizzled kb/vt (isolated retry of r14's (a)):
// linear LDS dest, per-lane swizzled global source, unchanged swizzled reads.
// No ds_writes, no staging VGPRs; __syncthreads drains vmcnt (m97 pattern).
// 4 waves x Q32, KVBLK=64, grid (16,32). Swapped QK^T, static max in C-init,
// truncation P-pack, l via mfma(P, ones).
// ---------------------------------------------------------------------------
__global__ __launch_bounds__(256) void attn_mfma(
    const u16* __restrict__ qb, const u16* __restrict__ kb,
    const u16* __restrict__ vt, u16* __restrict__ aob)
{
  __shared__ __align__(16) short Kl[2][64*64];   // 16KB [key][dim] swizzled
  __shared__ __align__(16) short Vl[2][64*64];   // 16KB [dim][key] swizzled
  __shared__ __align__(16) short Pl[4][32*64];   // 16KB per-wave [32q][64k]

  const int tid  = threadIdx.x;
  const int w    = tid >> 6;
  const int lane = tid & 63;
  const int c    = lane & 15;
  const int g    = lane >> 4;
  const int bh   = blockIdx.y, b = bh >> 3, h = bh & 7;
  const int qbase = blockIdx.x * 128 + w * 32;
  const int xr   = (c & 7) << 4;

  short8 qf[2][2];
  #pragma unroll
  for (int u = 0; u < 2; ++u){
    const u16* qrow = qb + ((size_t)(b*N_) + qbase + u*16 + c) * INNER + h * DH;
    qf[u][0] = *(const short8*)(qrow + g*8);
    qf[u][1] = *(const short8*)(qrow + 32 + g*8);
  }

  f32x4 o[2][4] = {};              // [qhalf][dimblock]: row=q g*4+r, col=dim c
  f32x4 lacc[2] = {};              // row-sums of P (same row layout as o)
  const short8 ones = {0x3F80,0x3F80,0x3F80,0x3F80,0x3F80,0x3F80,0x3F80,0x3F80};

  const u16* kbase = kb + (size_t)bh * MKP * DH;
  const u16* vbase = vt + (size_t)bh * DH * MKP;
  const int srw = w*8 + (lane >> 3);   // staging row (wave covers 8 rows/half)
  const int sck = (lane & 7) * 8;      // u16 offset of this lane's 16B chunk

  // async stage of tile kt into buffer buf; completes at next __syncthreads.
  // LDS image = identical to the old ds_write staging (slot x holds chunk
  // x^(row&7), via producer pre-swizzle), so all reads are unchanged.
  #define STAGE(buf, kt)                                                       \
    gload16(kbase + (size_t)((kt)*64 +      srw) * DH + sck,                   \
            (char*)Kl[buf] +        w*1024);                                   \
    gload16(kbase + (size_t)((kt)*64 + 32 + srw) * DH + sck,                   \
            (char*)Kl[buf] + 4096 + w*1024);                                   \
    gload16(vbase + (size_t)(     srw) * MKP + (kt)*64 + sck,                  \
            (char*)Vl[buf] +        w*1024);                                   \
    gload16(vbase + (size_t)(32 + srw) * MKP + (kt)*64 + sck,                  \
            (char*)Vl[buf] + 4096 + w*1024);

  STAGE(0, 0);

  int cur = 0;
  for (int kt = 0; kt < 33; ++kt){
    __syncthreads();                     // barrier + vmcnt(0): buf[cur] ready
    if (kt < 32){ STAGE(cur ^ 1, kt + 1); }

    const char* Kc = (const char*)Kl[cur];
    const char* Vc = (const char*)Vl[cur];
    char*       Pw = (char*)Pl + w*4096;

    // ---- swapped QK^T: each kf pair feeds BOTH query halves ----
    f32x4 sv[2][4];
    __builtin_amdgcn_s_setprio(1);
    #pragma unroll
    for (int s = 0; s < 4; ++s){
      const int row = s*16 + c;
      short8 kf0 = *(const short8*)(Kc + row*128 + ((     g*16) ^ xr));
      short8 kf1 = *(const short8*)(Kc + row*128 + ((64 + g*16) ^ xr));
      f32x4 a0 = {SM_BIAS, SM_BIAS, SM_BIAS, SM_BIAS};
      f32x4 a1 = {SM_BIAS, SM_BIAS, SM_BIAS, SM_BIAS};
      a0 = __builtin_amdgcn_mfma_f32_16x16x32_bf16(kf0, qf[0][0], a0, 0, 0, 0);
      a1 = __builtin_amdgcn_mfma_f32_16x16x32_bf16(kf0, qf[1][0], a1, 0, 0, 0);
      a0 = __builtin_amdgcn_mfma_f32_16x16x32_bf16(kf1, qf[0][1], a0, 0, 0, 0);
      a1 = __builtin_amdgcn_mfma_f32_16x16x32_bf16(kf1, qf[1][1], a1, 0, 0, 0);
      sv[0][s] = a0; sv[1][s] = a1;
    }
    __builtin_amdgcn_s_setprio(0);

    if (kt == 32){                    // only key 2048 (tile-local 0) is valid
      #pragma unroll
      for (int u = 0; u < 2; ++u)
        #pragma unroll
        for (int s = 0; s < 4; ++s)
          #pragma unroll
          for (int r = 0; r < 4; ++r)
            if (s | r) sv[u][s][r] = -1e30f;
      if (g){ sv[0][0][0] = -1e30f; sv[1][0][0] = -1e30f; }
    }

    // ---- softmax numerators: p = exp2(sv), truncation-pack, store to Pl ----
    #pragma unroll
    for (int u = 0; u < 2; ++u){
      #pragma unroll
      for (int s = 0; s < 4; ++s){
        const float p0 = EXP2(sv[u][s][0]);
        const float p1 = EXP2(sv[u][s][1]);
        const float p2 = EXP2(sv[u][s][2]);
        const float p3 = EXP2(sv[u][s][3]);
        uint2 pk;
        pk.x = bfpk_tr(p0, p1);
        pk.y = bfpk_tr(p2, p3);
        *(uint2*)(Pw + (u*16 + c)*128
                  + ((((2*s + (g>>1)) ^ (c&7)) << 4) | ((g&1)*8))) = pk;
      }
    }

    // ---- PV + l: each vf feeds BOTH query halves; l via mfma(P, ones) ----
    __builtin_amdgcn_s_setprio(1);
    #pragma unroll
    for (int hh = 0; hh < 2; ++hh){
      short8 pf0 = *(const short8*)(Pw + (     c)*128 + (((hh*4 + g) ^ (c&7)) << 4));
      short8 pf1 = *(const short8*)(Pw + (16 + c)*128 + (((hh*4 + g) ^ (c&7)) << 4));
      lacc[0] = __builtin_amdgcn_mfma_f32_16x16x32_bf16(pf0, ones, lacc[0], 0, 0, 0);
      lacc[1] = __builtin_amdgcn_mfma_f32_16x16x32_bf16(pf1, ones, lacc[1], 0, 0, 0);
      #pragma unroll
      for (int D = 0; D < 4; ++D){
        short8 vf = *(const short8*)(Vc + (D*16 + c)*128 + ((hh*64 + g*16) ^ xr));
        o[0][D] = __builtin_amdgcn_mfma_f32_16x16x32_bf16(pf0, vf, o[0][D], 0, 0, 0);
        o[1][D] = __builtin_amdgcn_mfma_f32_16x16x32_bf16(pf1, vf, o[1][D], 0, 0, 0);
      }
    }
    __builtin_amdgcn_s_setprio(0);

    if (kt < 32) cur ^= 1;
  }

  // ---- epilogue: l row-aligned with o -> no shuffles ----
  #pragma unroll
  for (int u = 0; u < 2; ++u){
    #pragma unroll
    for (int r = 0; r < 4; ++r){
      const float ir = 1.f / lacc[u][r];
      const size_t nrow = (size_t)(b*N_) + qbase + u*16 + g*4 + r;
      #pragma unroll
      for (int D = 0; D < 4; ++D)
        aob[nrow * INNER + h*DH + D*16 + c] = bfc(o[u][D][r] * ir);
    }
  }
}

extern "C" void kernel_launch(void* const* d_in, const int* in_sizes, int n_in,
                              void* d_out, int out_size, void* d_ws, size_t ws_size,
                              hipStream_t stream)
{
  const float* x    = (const float*)d_in[0];
  const float* ctx  = (const float*)d_in[1];
  const float* Wq   = (const float*)d_in[2];
  const float* Wkv  = (const float*)d_in[3];
  const float* nk   = (const float*)d_in[4];
  const float* nv   = (const float*)d_in[5];
  const float* Wout = (const float*)d_in[6];
  const float* bout = (const float*)d_in[7];
  float* out = (float*)d_out;

  char* ws = (char*)d_ws;
  u16* xb    = (u16*)(ws);                       //  8,388,608
  u16* cb    = (u16*)(ws +  8388608);            //  8,388,608
  u16* qb    = (u16*)(ws + 16777216);            //  8,388,608
  u16* kbB   = (u16*)(ws + 25165824);            //  8,650,752
  u16* vtb   = (u16*)(ws + 33816576);            //  8,650,752
  u16* Wqt   = (u16*)(ws + 42467328);            //    524,288
  u16* Wkvt  = (u16*)(ws + 42991616);            //  1,048,576
  u16* Woutt = (u16*)(ws + 44040192);            //    524,288  (end ~44.6MB)
  u16* aoB   = xb;                               // alias: xb dead after proj

  // merged prep: converts + weight transposes + null-token fill, one dispatch
  prep<<<4488, 256, 0, stream>>>(x, ctx, Wq, Wkv, Wout, nk, nv,
                                 xb, cb, Wqt, Wkvt, Woutt, kbB, vtb);

  // fused q + kv projections; k/v^T written pre-swizzled, v directly transposed
  fused_proj<<<768, 256, 0, stream>>>(xb, cb, Wqt, Wkvt, qb, kbB, vtb);
  // MFMA flash attention (global_load_lds staging) -> ao bf16 (aliases xb)
  attn_mfma<<<dim3(16, 32), 256, 0, stream>>>(qb, kbB, vtb, aoB);
  // out = ao @ Wout + bout (128x64 tiles, 512 blocks, depth-2, fp32 out)
  mgemm_out<<<512, 256, 0, stream>>>(aoB, Woutt, out, bout);
}

// Round 22
// 101.034 us; speedup vs baseline: 1.0258x; 1.0258x over previous
//
#include <hip/hip_runtime.h>
#include <hip/hip_bf16.h>
#include <stdint.h>

#define B_    4
#define N_    2048
#define M_    2048
#define DIMX  512
#define INNER 512
#define H_    8
#define DH    64
#define MK    2049   // M+1 keys; null token lives at key index 2048 (slot order
                     // is irrelevant to softmax -> enables aligned v^T writes)
#define MKP   2112   // padded to 33 tiles of 64 (tail masked in-kernel)

#define QSCALE  0.18033688011f   // 0.125 * log2(e): softmax in exp2 domain
#define SM_BIAS -11.5415605f     // static softmax max: |S_log2| <= 64*QSCALE

using u16 = unsigned short;
using u32 = unsigned int;

typedef __attribute__((ext_vector_type(8))) short short8;
typedef __attribute__((ext_vector_type(4))) float f32x4;

#if defined(__has_builtin)
# if __has_builtin(__builtin_amdgcn_exp2f)
#  define EXP2(x) __builtin_amdgcn_exp2f(x)
# endif
#endif
#ifndef EXP2
# define EXP2(x) exp2f(x)
#endif

__device__ __forceinline__ u16 bfc(float f){
  __hip_bfloat16 h = __float2bfloat16(f);
  return *reinterpret_cast<u16*>(&h);
}
__device__ __forceinline__ u32 bfpk(float lo, float hi){
  return (u32)bfc(lo) | ((u32)bfc(hi) << 16);
}
// Truncation pack for P only: downward bias cancels to first order in
// O = (P@V)/(P@ones) since numerator and denominator use the SAME bits.
__device__ __forceinline__ u32 bfpk_tr(float lo, float hi){
  union { float f; u32 u; } a, b; a.f = lo; b.f = hi;
  return (a.u >> 16) | (b.u & 0xffff0000u);
}

// ---------------------------------------------------------------------------
// Merged prep: one dispatch.
//  blocks [0, 2048)     : x  fp32 -> bf16 (8 elems/thread)
//  blocks [2048, 4096)  : ctx fp32 -> bf16
//  blocks [4096, 4480)  : weight transposes fp32 [R][C] -> bf16 [C][R]
//  blocks [4480, 4488)  : null token fill at key index 2048 (k & v^T)
// Separate from the GEMM is deliberate (r11 lesson): cold HBM reads happen
// here at streaming BW; fused_proj then reads L3-warm bf16.
// ---------------------------------------------------------------------------
__global__ __launch_bounds__(256) void prep(
    const float* __restrict__ x, const float* __restrict__ ctx,
    const float* __restrict__ Wq, const float* __restrict__ Wkv,
    const float* __restrict__ Wout,
    const float* __restrict__ nk, const float* __restrict__ nv,
    u16* __restrict__ xb, u16* __restrict__ cb,
    u16* __restrict__ Wqt, u16* __restrict__ Wkvt, u16* __restrict__ Woutt,
    u16* __restrict__ kb, u16* __restrict__ vt)
{
  const int bid = blockIdx.x;
  if (bid < 4096){                       // streaming converts
    const float* in = (bid < 2048) ? x : ctx;
    u16* out        = (bid < 2048) ? xb : cb;
    const int i = (bid & 2047) * 256 + threadIdx.x;
    float4 a = ((const float4*)in)[i*2];
    float4 b = ((const float4*)in)[i*2+1];
    uint4 t;
    t.x = bfpk(a.x, a.y); t.y = bfpk(a.z, a.w);
    t.z = bfpk(b.x, b.y); t.w = bfpk(b.z, b.w);
    ((uint4*)out)[i] = t;
    return;
  }
  if (bid >= 4480){                      // null token at key index 2048
    const int i = (bid - 4480) * 256 + threadIdx.x;  // 0..2047 = bh*64 + d
    const int d = i & 63, bh = i >> 6;
    kb[((size_t)bh * MKP + 2048) * DH + d] = bfc(tanhf(nk[d]));
    vt[((size_t)bh * DH + d) * MKP + 2048] = bfc(nv[d]);
    return;
  }
  // weight transposes: 384 blocks = 3 x (16 x 8)
  const int tt = bid - 4096;
  const int z  = tt >> 7;                // 0..2
  const int rem = tt & 127;
  const int cx = rem & 15, ry = rem >> 4;
  const float* in = (z == 0) ? Wq : (z == 1) ? Wkv : Wout;
  u16* out        = (z == 0) ? Wqt : (z == 1) ? Wkvt : Woutt;
  const int C     = (z == 1) ? 1024 : 512;
  const int R     = 512;
  if (cx * 64 >= C) return;

  __shared__ float tl[64][65];
  const int t = threadIdx.x;
  const int c0 = cx * 64, r0 = ry * 64;
  const int col = t & 63, rb = t >> 6;
  #pragma unroll
  for (int j = 0; j < 16; ++j){
    const int row = rb + j*4;
    tl[row][col] = in[(size_t)(r0 + row) * C + c0 + col];
  }
  __syncthreads();
  #pragma unroll
  for (int j = 0; j < 16; ++j){
    const int orow = rb + j*4;
    out[(size_t)(c0 + orow) * R + r0 + col] = bfc(tl[col][orow]);
  }
}

// frag-read + 16 MFMA from LDS buffer `bi` (compile-time)
#define PROJ_COMPUTE(bi)                                                      \
  {                                                                           \
    short8 af[4], bf[4];                                                      \
    _Pragma("unroll")                                                         \
    for (int m = 0; m < 4; ++m){                                              \
      const int row = wr + m*16 + c;                                          \
      af[m] = *(const short8*)((char*)At[bi] + row*64 + ((g ^ ((row>>1)&3)) << 4)); \
    }                                                                         \
    _Pragma("unroll")                                                         \
    for (int n = 0; n < 4; ++n){                                              \
      const int row = wc + n*16 + c;                                          \
      bf[n] = *(const short8*)((char*)Bl[bi] + row*64 + ((g ^ ((row>>1)&3)) << 4)); \
    }                                                                         \
    __builtin_amdgcn_s_setprio(1);                                            \
    _Pragma("unroll")                                                         \
    for (int m = 0; m < 4; ++m)                                               \
      _Pragma("unroll")                                                       \
      for (int n = 0; n < 4; ++n)                                             \
        acc[m][n] = __builtin_amdgcn_mfma_f32_16x16x32_bf16(af[m], bf[n], acc[m][n], 0, 0, 0); \
    __builtin_amdgcn_s_setprio(0);                                            \
  }

// ---------------------------------------------------------------------------
// Fused q + kv projection GEMM, all-bf16 inputs. 768 blocks (XCD-chunked):
// tile<256 -> q (gx=4), else kv (gx=8). 128x128 tile, BK=32, 16 K-steps.
// Depth-2 register prefetch + double-buffered LDS. v is written DIRECTLY in
// transposed [bh][d][m] layout (aligned uint2 per (m,n): the 4 acc rows are
// consecutive in m) — vtrans pass deleted (r20). [r21's global_load_lds
// staging variant REVERTED: correct (absmax identical) but +2.4 us — the
// ds_writes it removed weren't on the critical path, and the scattered
// pre-swizzled k-epilogue writes cost more than the staging saved.]
// ---------------------------------------------------------------------------
__global__ __launch_bounds__(256, 3) void fused_proj(
    const u16* __restrict__ xb, const u16* __restrict__ cb,
    const u16* __restrict__ Wqt, const u16* __restrict__ Wkvt,
    u16* __restrict__ qb, u16* __restrict__ kb, u16* __restrict__ vt)
{
  __shared__ __align__(16) short At[2][128*32];
  __shared__ __align__(16) short Bl[2][128*32];

  const int flat = blockIdx.x;
  const int tile = (flat & 7) * 96 + (flat >> 3);    // XCD-chunked, bijective
  const bool isq = tile < 256;
  const int lt   = isq ? tile : tile - 256;
  const int gx   = isq ? 4 : 8;
  const int row0 = (lt / gx) * 128, col0 = (lt % gx) * 128;
  const u16* A  = isq ? xb : cb;
  const u16* Bt = isq ? Wqt : Wkvt;

  const int tid = threadIdx.x;
  const int w = tid >> 6, lane = tid & 63;
  const int c = lane & 15, g = lane >> 4;
  const int wr = (w >> 1) * 64, wc = (w & 1) * 64;

  f32x4 acc[4][4] = {};

  const int srow = tid >> 1, sj = (tid & 1) * 2;
  const int swz0 = ((sj  ) ^ ((srow >> 1) & 3)) << 4;
  const int swz1 = ((sj+1) ^ ((srow >> 1) & 3)) << 4;

  const u16* asrc = A  + (size_t)(row0 + srow) * DIMX + sj*8;
  const u16* bsrc = Bt + (size_t)(col0 + srow) * DIMX + sj*8;

  uint4 aA0, aA1, bA0, bA1;      // slot A
  uint4 aB0, aB1, bB0, bB1;      // slot B

  aA0 = ((const uint4*)asrc)[0];        aA1 = ((const uint4*)asrc)[1];
  bA0 = ((const uint4*)bsrc)[0];        bA1 = ((const uint4*)bsrc)[1];
  aB0 = ((const uint4*)(asrc + 32))[0]; aB1 = ((const uint4*)(asrc + 32))[1];
  bB0 = ((const uint4*)(bsrc + 32))[0]; bB1 = ((const uint4*)(bsrc + 32))[1];
  *(uint4*)((char*)At[0] + srow*64 + swz0) = aA0;
  *(uint4*)((char*)At[0] + srow*64 + swz1) = aA1;
  *(uint4*)((char*)Bl[0] + srow*64 + swz0) = bA0;
  *(uint4*)((char*)Bl[0] + srow*64 + swz1) = bA1;

  for (int kk = 0; kk < 16; kk += 2){
    __syncthreads();
    if (kk + 2 < 16){
      const u16* an = asrc + (kk+2)*32;
      const u16* bn = bsrc + (kk+2)*32;
      aA0 = ((const uint4*)an)[0]; aA1 = ((const uint4*)an)[1];
      bA0 = ((const uint4*)bn)[0]; bA1 = ((const uint4*)bn)[1];
    }
    PROJ_COMPUTE(0);
    *(uint4*)((char*)At[1] + srow*64 + swz0) = aB0;   // tile kk+1 (always valid)
    *(uint4*)((char*)At[1] + srow*64 + swz1) = aB1;
    *(uint4*)((char*)Bl[1] + srow*64 + swz0) = bB0;
    *(uint4*)((char*)Bl[1] + srow*64 + swz1) = bB1;

    __syncthreads();
    if (kk + 3 < 16){
      const u16* an = asrc + (kk+3)*32;
      const u16* bn = bsrc + (kk+3)*32;
      aB0 = ((const uint4*)an)[0]; aB1 = ((const uint4*)an)[1];
      bB0 = ((const uint4*)bn)[0]; bB1 = ((const uint4*)bn)[1];
    }
    PROJ_COMPUTE(1);
    if (kk + 2 < 16){
      *(uint4*)((char*)At[0] + srow*64 + swz0) = aA0; // tile kk+2
      *(uint4*)((char*)At[0] + srow*64 + swz1) = aA1;
      *(uint4*)((char*)Bl[0] + srow*64 + swz0) = bA0;
      *(uint4*)((char*)Bl[0] + srow*64 + swz1) = bA1;
    }
  }

  #pragma unroll
  for (int m = 0; m < 4; ++m){
    #pragma unroll
    for (int n = 0; n < 4; ++n){
      const int R0  = row0 + wr + m*16 + g*4;
      const int col = col0 + wc + n*16 + c;
      if (isq){
        #pragma unroll
        for (int rr = 0; rr < 4; ++rr)
          qb[(size_t)(R0 + rr) * INNER + col] = bfc(tanhf(acc[m][n][rr]) * QSCALE);
      } else {
        const int bidx = R0 >> 11, mm = R0 & 2047;    // 4 rows share bidx
        if (col < INNER){
          const int h = col >> 6, d = col & 63;
          #pragma unroll
          for (int rr = 0; rr < 4; ++rr)
            kb[((size_t)(bidx*H_ + h) * MKP + mm + rr) * DH + d] =
                bfc(tanhf(acc[m][n][rr]));
        } else {
          const int cc = col - INNER;
          const int h = cc >> 6, d = cc & 63;
          uint2 o;                                     // 4 consecutive m -> 8B
          o.x = bfpk(acc[m][n][0], acc[m][n][1]);
          o.y = bfpk(acc[m][n][2], acc[m][n][3]);
          *(uint2*)(vt + ((size_t)(bidx*H_ + h) * DH + d) * MKP + mm) = o;
        }
      }
    }
  }
}

// ---------------------------------------------------------------------------
// Out-projection GEMM: out = ao @ Wout^T + bias. 128x64 tiles, 512 blocks.
// ---------------------------------------------------------------------------
__global__ __launch_bounds__(256, 3) void mgemm_out(
    const u16* __restrict__ A, const u16* __restrict__ Bt,
    float* __restrict__ Cf, const float* __restrict__ bias)
{
  __shared__ __align__(16) short At[2][128*32];   // 8KB each
  __shared__ __align__(16) short Bl[2][64*32];    // 4KB each

  const int flat = blockIdx.x;                       // 512 blocks
  const int tile = (flat & 7) * 64 + (flat >> 3);    // XCD-chunked, bijective
  const int row0 = (tile >> 3) * 128, col0 = (tile & 7) * 64;

  const int tid = threadIdx.x;
  const int w = tid >> 6, lane = tid & 63;
  const int c = lane & 15, g = lane >> 4;
  const int wr = (w >> 1) * 64, wc = (w & 1) * 32;

  f32x4 acc[4][2] = {};

  const int srow = tid >> 1, sj = (tid & 1) * 2;
  const int swz0 = ((sj  ) ^ ((srow >> 1) & 3)) << 4;
  const int swz1 = ((sj+1) ^ ((srow >> 1) & 3)) << 4;
  const int brow = tid >> 2, bch = tid & 3;
  const int bswz = (bch ^ ((brow >> 1) & 3)) << 4;

  const u16* asrc = A  + (size_t)(row0 + srow) * INNER + sj*8;
  const u16* bsrc = Bt + (size_t)(col0 + brow) * INNER + bch*8;

  uint4 aA0, aA1, bA0;
  uint4 aB0, aB1, bB0;

  aA0 = ((const uint4*)asrc)[0];        aA1 = ((const uint4*)asrc)[1];
  bA0 = *(const uint4*)bsrc;
  aB0 = ((const uint4*)(asrc + 32))[0]; aB1 = ((const uint4*)(asrc + 32))[1];
  bB0 = *(const uint4*)(bsrc + 32);
  *(uint4*)((char*)At[0] + srow*64 + swz0) = aA0;
  *(uint4*)((char*)At[0] + srow*64 + swz1) = aA1;
  *(uint4*)((char*)Bl[0] + brow*64 + bswz) = bA0;

  for (int kk = 0; kk < 16; kk += 2){
    __syncthreads();
    if (kk + 2 < 16){
      const u16* an = asrc + (kk+2)*32;
      aA0 = ((const uint4*)an)[0]; aA1 = ((const uint4*)an)[1];
      bA0 = *(const uint4*)(bsrc + (kk+2)*32);
    }
    {
      short8 af[4], bf[2];
      #pragma unroll
      for (int m = 0; m < 4; ++m){
        const int row = wr + m*16 + c;
        af[m] = *(const short8*)((char*)At[0] + row*64 + ((g ^ ((row>>1)&3)) << 4));
      }
      #pragma unroll
      for (int n = 0; n < 2; ++n){
        const int row = wc + n*16 + c;
        bf[n] = *(const short8*)((char*)Bl[0] + row*64 + ((g ^ ((row>>1)&3)) << 4));
      }
      __builtin_amdgcn_s_setprio(1);
      #pragma unroll
      for (int m = 0; m < 4; ++m)
        #pragma unroll
        for (int n = 0; n < 2; ++n)
          acc[m][n] = __builtin_amdgcn_mfma_f32_16x16x32_bf16(af[m], bf[n], acc[m][n], 0, 0, 0);
      __builtin_amdgcn_s_setprio(0);
    }
    *(uint4*)((char*)At[1] + srow*64 + swz0) = aB0;   // tile kk+1
    *(uint4*)((char*)At[1] + srow*64 + swz1) = aB1;
    *(uint4*)((char*)Bl[1] + brow*64 + bswz) = bB0;

    __syncthreads();
    if (kk + 3 < 16){
      const u16* an = asrc + (kk+3)*32;
      aB0 = ((const uint4*)an)[0]; aB1 = ((const uint4*)an)[1];
      bB0 = *(const uint4*)(bsrc + (kk+3)*32);
    }
    {
      short8 af[4], bf[2];
      #pragma unroll
      for (int m = 0; m < 4; ++m){
        const int row = wr + m*16 + c;
        af[m] = *(const short8*)((char*)At[1] + row*64 + ((g ^ ((row>>1)&3)) << 4));
      }
      #pragma unroll
      for (int n = 0; n < 2; ++n){
        const int row = wc + n*16 + c;
        bf[n] = *(const short8*)((char*)Bl[1] + row*64 + ((g ^ ((row>>1)&3)) << 4));
      }
      __builtin_amdgcn_s_setprio(1);
      #pragma unroll
      for (int m = 0; m < 4; ++m)
        #pragma unroll
        for (int n = 0; n < 2; ++n)
          acc[m][n] = __builtin_amdgcn_mfma_f32_16x16x32_bf16(af[m], bf[n], acc[m][n], 0, 0, 0);
      __builtin_amdgcn_s_setprio(0);
    }
    if (kk + 2 < 16){
      *(uint4*)((char*)At[0] + srow*64 + swz0) = aA0; // tile kk+2
      *(uint4*)((char*)At[0] + srow*64 + swz1) = aA1;
      *(uint4*)((char*)Bl[0] + brow*64 + bswz) = bA0;
    }
  }

  #pragma unroll
  for (int m = 0; m < 4; ++m){
    #pragma unroll
    for (int n = 0; n < 2; ++n){
      #pragma unroll
      for (int rr = 0; rr < 4; ++rr){
        const int R = row0 + wr + m*16 + g*4 + rr;
        const int col = col0 + wc + n*16 + c;
        Cf[(size_t)R * 512 + col] = acc[m][n][rr] + bias[col];
      }
    }
  }
}

// ---------------------------------------------------------------------------
// MFMA flash attention — r17/r20 best config. 4 waves x Q32, KVBLK=64, grid
// (16,32), LDS 48KB. Register-prefetch + ds_write staging (r21's
// global_load_lds variant reverted: correct but slower here). Swapped QK^T,
// static max in MFMA C-init, truncation P-pack, l via mfma(P, ones).
// Null token at key index 2048 (= the slot the tail mask keeps).
// ---------------------------------------------------------------------------
__global__ __launch_bounds__(256) void attn_mfma(
    const u16* __restrict__ qb, const u16* __restrict__ kb,
    const u16* __restrict__ vt, u16* __restrict__ aob)
{
  __shared__ __align__(16) short Kl[2][64*64];   // 16KB [key][dim] swizzled
  __shared__ __align__(16) short Vl[2][64*64];   // 16KB [dim][key] swizzled
  __shared__ __align__(16) short Pl[4][32*64];   // 16KB per-wave [32q][64k]

  const int tid  = threadIdx.x;
  const int w    = tid >> 6;
  const int lane = tid & 63;
  const int c    = lane & 15;
  const int g    = lane >> 4;
  const int bh   = blockIdx.y, b = bh >> 3, h = bh & 7;
  const int qbase = blockIdx.x * 128 + w * 32;
  const int xr   = (c & 7) << 4;

  short8 qf[2][2];
  #pragma unroll
  for (int u = 0; u < 2; ++u){
    const u16* qrow = qb + ((size_t)(b*N_) + qbase + u*16 + c) * INNER + h * DH;
    qf[u][0] = *(const short8*)(qrow + g*8);
    qf[u][1] = *(const short8*)(qrow + 32 + g*8);
  }

  f32x4 o[2][4] = {};              // [qhalf][dimblock]: row=q g*4+r, col=dim c
  f32x4 lacc[2] = {};              // row-sums of P (same row layout as o)
  const short8 ones = {0x3F80,0x3F80,0x3F80,0x3F80,0x3F80,0x3F80,0x3F80,0x3F80};

  const u16* kbase = kb + (size_t)bh * MKP * DH;
  const u16* vbase = vt + (size_t)bh * DH * MKP;
  const int srow = tid >> 2, sch = (tid & 3) * 2;
  const int swz0 = ((sch  ) ^ (srow & 7)) << 4;
  const int swz1 = ((sch+1) ^ (srow & 7)) << 4;

  uint4 rk0, rk1, rv0, rv1;
  {
    const u16* ksrc = kbase + (size_t)srow * DH + sch*8;
    rk0 = ((const uint4*)ksrc)[0]; rk1 = ((const uint4*)ksrc)[1];
    const u16* vsrc = vbase + (size_t)srow * MKP + sch*8;
    rv0 = ((const uint4*)vsrc)[0]; rv1 = ((const uint4*)vsrc)[1];
  }
  *(uint4*)((char*)Kl[0] + srow*128 + swz0) = rk0;
  *(uint4*)((char*)Kl[0] + srow*128 + swz1) = rk1;
  *(uint4*)((char*)Vl[0] + srow*128 + swz0) = rv0;
  *(uint4*)((char*)Vl[0] + srow*128 + swz1) = rv1;

  int cur = 0;
  for (int kt = 0; kt < 33; ++kt){
    __syncthreads();
    if (kt < 32){
      const u16* ksrc = kbase + (size_t)((kt+1)*64 + srow) * DH + sch*8;
      rk0 = ((const uint4*)ksrc)[0]; rk1 = ((const uint4*)ksrc)[1];
      const u16* vsrc = vbase + (size_t)srow * MKP + (kt+1)*64 + sch*8;
      rv0 = ((const uint4*)vsrc)[0]; rv1 = ((const uint4*)vsrc)[1];
    }

    const char* Kc = (const char*)Kl[cur];
    const char* Vc = (const char*)Vl[cur];
    char*       Pw = (char*)Pl + w*4096;

    // ---- swapped QK^T: each kf pair feeds BOTH query halves ----
    f32x4 sv[2][4];
    __builtin_amdgcn_s_setprio(1);
    #pragma unroll
    for (int s = 0; s < 4; ++s){
      const int row = s*16 + c;
      short8 kf0 = *(const short8*)(Kc + row*128 + ((     g*16) ^ xr));
      short8 kf1 = *(const short8*)(Kc + row*128 + ((64 + g*16) ^ xr));
      f32x4 a0 = {SM_BIAS, SM_BIAS, SM_BIAS, SM_BIAS};
      f32x4 a1 = {SM_BIAS, SM_BIAS, SM_BIAS, SM_BIAS};
      a0 = __builtin_amdgcn_mfma_f32_16x16x32_bf16(kf0, qf[0][0], a0, 0, 0, 0);
      a1 = __builtin_amdgcn_mfma_f32_16x16x32_bf16(kf0, qf[1][0], a1, 0, 0, 0);
      a0 = __builtin_amdgcn_mfma_f32_16x16x32_bf16(kf1, qf[0][1], a0, 0, 0, 0);
      a1 = __builtin_amdgcn_mfma_f32_16x16x32_bf16(kf1, qf[1][1], a1, 0, 0, 0);
      sv[0][s] = a0; sv[1][s] = a1;
    }
    __builtin_amdgcn_s_setprio(0);

    if (kt == 32){                    // only key 2048 (tile-local 0) is valid
      #pragma unroll
      for (int u = 0; u < 2; ++u)
        #pragma unroll
        for (int s = 0; s < 4; ++s)
          #pragma unroll
          for (int r = 0; r < 4; ++r)
            if (s | r) sv[u][s][r] = -1e30f;
      if (g){ sv[0][0][0] = -1e30f; sv[1][0][0] = -1e30f; }
    }

    // ---- softmax numerators: p = exp2(sv), truncation-pack, store to Pl ----
    #pragma unroll
    for (int u = 0; u < 2; ++u){
      #pragma unroll
      for (int s = 0; s < 4; ++s){
        const float p0 = EXP2(sv[u][s][0]);
        const float p1 = EXP2(sv[u][s][1]);
        const float p2 = EXP2(sv[u][s][2]);
        const float p3 = EXP2(sv[u][s][3]);
        uint2 pk;
        pk.x = bfpk_tr(p0, p1);
        pk.y = bfpk_tr(p2, p3);
        *(uint2*)(Pw + (u*16 + c)*128
                  + ((((2*s + (g>>1)) ^ (c&7)) << 4) | ((g&1)*8))) = pk;
      }
    }

    // ---- PV + l: each vf feeds BOTH query halves; l via mfma(P, ones) ----
    __builtin_amdgcn_s_setprio(1);
    #pragma unroll
    for (int hh = 0; hh < 2; ++hh){
      short8 pf0 = *(const short8*)(Pw + (     c)*128 + (((hh*4 + g) ^ (c&7)) << 4));
      short8 pf1 = *(const short8*)(Pw + (16 + c)*128 + (((hh*4 + g) ^ (c&7)) << 4));
      lacc[0] = __builtin_amdgcn_mfma_f32_16x16x32_bf16(pf0, ones, lacc[0], 0, 0, 0);
      lacc[1] = __builtin_amdgcn_mfma_f32_16x16x32_bf16(pf1, ones, lacc[1], 0, 0, 0);
      #pragma unroll
      for (int D = 0; D < 4; ++D){
        short8 vf = *(const short8*)(Vc + (D*16 + c)*128 + ((hh*64 + g*16) ^ xr));
        o[0][D] = __builtin_amdgcn_mfma_f32_16x16x32_bf16(pf0, vf, o[0][D], 0, 0, 0);
        o[1][D] = __builtin_amdgcn_mfma_f32_16x16x32_bf16(pf1, vf, o[1][D], 0, 0, 0);
      }
    }
    __builtin_amdgcn_s_setprio(0);

    if (kt < 32){
      char* Kn = (char*)Kl[cur ^ 1];
      char* Vn = (char*)Vl[cur ^ 1];
      *(uint4*)(Kn + srow*128 + swz0) = rk0;
      *(uint4*)(Kn + srow*128 + swz1) = rk1;
      *(uint4*)(Vn + srow*128 + swz0) = rv0;
      *(uint4*)(Vn + srow*128 + swz1) = rv1;
      cur ^= 1;
    }
  }

  // ---- epilogue: l row-aligned with o -> no shuffles ----
  #pragma unroll
  for (int u = 0; u < 2; ++u){
    #pragma unroll
    for (int r = 0; r < 4; ++r){
      const float ir = 1.f / lacc[u][r];
      const size_t nrow = (size_t)(b*N_) + qbase + u*16 + g*4 + r;
      #pragma unroll
      for (int D = 0; D < 4; ++D)
        aob[nrow * INNER + h*DH + D*16 + c] = bfc(o[u][D][r] * ir);
    }
  }
}

extern "C" void kernel_launch(void* const* d_in, const int* in_sizes, int n_in,
                              void* d_out, int out_size, void* d_ws, size_t ws_size,
                              hipStream_t stream)
{
  const float* x    = (const float*)d_in[0];
  const float* ctx  = (const float*)d_in[1];
  const float* Wq   = (const float*)d_in[2];
  const float* Wkv  = (const float*)d_in[3];
  const float* nk   = (const float*)d_in[4];
  const float* nv   = (const float*)d_in[5];
  const float* Wout = (const float*)d_in[6];
  const float* bout = (const float*)d_in[7];
  float* out = (float*)d_out;

  char* ws = (char*)d_ws;
  u16* xb    = (u16*)(ws);                       //  8,388,608
  u16* cb    = (u16*)(ws +  8388608);            //  8,388,608
  u16* qb    = (u16*)(ws + 16777216);            //  8,388,608
  u16* kbB   = (u16*)(ws + 25165824);            //  8,650,752
  u16* vtb   = (u16*)(ws + 33816576);            //  8,650,752
  u16* Wqt   = (u16*)(ws + 42467328);            //    524,288
  u16* Wkvt  = (u16*)(ws + 42991616);            //  1,048,576
  u16* Woutt = (u16*)(ws + 44040192);            //    524,288  (end ~44.6MB)
  u16* aoB   = xb;                               // alias: xb dead after proj

  // merged prep: converts + weight transposes + null-token fill, one dispatch
  prep<<<4488, 256, 0, stream>>>(x, ctx, Wq, Wkv, Wout, nk, nv,
                                 xb, cb, Wqt, Wkvt, Woutt, kbB, vtb);

  // fused q + kv projections; v written directly transposed (vtrans deleted)
  fused_proj<<<768, 256, 0, stream>>>(xb, cb, Wqt, Wkvt, qb, kbB, vtb);
  // MFMA flash attention (r17/r20 best config) -> ao bf16 (aliases xb)
  attn_mfma<<<dim3(16, 32), 256, 0, stream>>>(qb, kbB, vtb, aoB);
  // out = ao @ Wout + bout (128x64 tiles, 512 blocks, depth-2, fp32 out)
  mgemm_out<<<512, 256, 0, stream>>>(aoB, Woutt, out, bout);
}